// Round 1
// baseline (770.541 us; speedup 1.0000x reference)
//
#include <hip/hip_runtime.h>
#include <math.h>

#define NN 50000
#define EE 500000
#define DIN 384
#define HIDD 128
#define NHEAD 8
#define CHAN 16
#define OUTD 16

// ---------------- CSR build ----------------
__global__ void zero_ints(int* p, int n) {
  int i = blockIdx.x * blockDim.x + threadIdx.x;
  if (i < n) p[i] = 0;
}

__global__ void hist_kernel(const int* __restrict__ dst, int* __restrict__ counts, int e) {
  int i = blockIdx.x * blockDim.x + threadIdx.x;
  if (i < e) atomicAdd(&counts[dst[i]], 1);
}

// single-block exclusive scan (n up to ~64K), writes rowptr[0..n] and woff[0..n-1]
__global__ __launch_bounds__(1024) void scan_kernel(const int* __restrict__ counts,
                                                    int* __restrict__ rowptr,
                                                    int* __restrict__ woff, int n) {
  __shared__ int buf[1024];
  __shared__ int carry_s;
  if (threadIdx.x == 0) carry_s = 0;
  __syncthreads();
  for (int base = 0; base < n; base += 1024) {
    int i = base + threadIdx.x;
    int v = (i < n) ? counts[i] : 0;
    buf[threadIdx.x] = v;
    __syncthreads();
    #pragma unroll
    for (int off = 1; off < 1024; off <<= 1) {
      int t = (threadIdx.x >= off) ? buf[threadIdx.x - off] : 0;
      __syncthreads();
      buf[threadIdx.x] += t;
      __syncthreads();
    }
    int excl = buf[threadIdx.x] - v;
    if (i < n) { int r = carry_s + excl; rowptr[i] = r; woff[i] = r; }
    __syncthreads();
    if (threadIdx.x == 1023) carry_s += buf[1023];
    __syncthreads();
  }
  if (threadIdx.x == 0) rowptr[n] = carry_s;
}

__global__ void scatter_kernel(const int* __restrict__ src, const int* __restrict__ dst,
                               int* __restrict__ woff, int* __restrict__ col, int e) {
  int i = blockIdx.x * blockDim.x + threadIdx.x;
  if (i < e) {
    int p = atomicAdd(&woff[dst[i]], 1);
    col[p] = src[i];
  }
}

// ---------------- GEMM: C[M,128] = A[M,K] @ B[K,128], optional bias+relu ----------------
template<bool RELU_BIAS>
__global__ __launch_bounds__(256) void gemm_n128(const float* __restrict__ A,
                                                 const float* __restrict__ B,
                                                 const float* __restrict__ bias,
                                                 float* __restrict__ C, int M, int K) {
  __shared__ float sA[64][17];   // [row][k], +1 pad breaks bank aliasing on k-reads
  __shared__ float sB[16][128];  // [k][col]
  const int tid = threadIdx.x;
  const int tx = tid & 15;       // col group: 8 cols
  const int ty = tid >> 4;       // row group: 4 rows
  const int m0 = blockIdx.x * 64;

  const int arow = tid >> 2;         // 0..63
  const int akq  = (tid & 3) * 4;    // 0,4,8,12
  const int brow = tid >> 4;         // 0..15
  const int bcol = (tid & 15) * 8;   // 0..120

  float acc[4][8];
  #pragma unroll
  for (int i = 0; i < 4; i++)
    #pragma unroll
    for (int j = 0; j < 8; j++) acc[i][j] = 0.f;

  const bool aval = (m0 + arow) < M;
  const float* Arow = A + (size_t)(m0 + arow) * K;

  for (int k0 = 0; k0 < K; k0 += 16) {
    float4 av = make_float4(0.f, 0.f, 0.f, 0.f);
    if (aval) av = *(const float4*)(Arow + k0 + akq);
    float4 bv0 = *(const float4*)(B + (size_t)(k0 + brow) * 128 + bcol);
    float4 bv1 = *(const float4*)(B + (size_t)(k0 + brow) * 128 + bcol + 4);
    __syncthreads();
    sA[arow][akq + 0] = av.x; sA[arow][akq + 1] = av.y;
    sA[arow][akq + 2] = av.z; sA[arow][akq + 3] = av.w;
    *(float4*)&sB[brow][bcol]     = bv0;
    *(float4*)&sB[brow][bcol + 4] = bv1;
    __syncthreads();
    #pragma unroll
    for (int k = 0; k < 16; k++) {
      float aa[4];
      #pragma unroll
      for (int i = 0; i < 4; i++) aa[i] = sA[ty * 4 + i][k];
      float4 b0 = *(const float4*)&sB[k][tx * 8];
      float4 b1 = *(const float4*)&sB[k][tx * 8 + 4];
      float bb[8] = {b0.x, b0.y, b0.z, b0.w, b1.x, b1.y, b1.z, b1.w};
      #pragma unroll
      for (int i = 0; i < 4; i++)
        #pragma unroll
        for (int j = 0; j < 8; j++) acc[i][j] = fmaf(aa[i], bb[j], acc[i][j]);
    }
  }
  #pragma unroll
  for (int i = 0; i < 4; i++) {
    int row = m0 + ty * 4 + i;
    if (row < M) {
      #pragma unroll
      for (int j = 0; j < 8; j++) {
        int colc = tx * 8 + j;
        float v = acc[i][j];
        if (RELU_BIAS) { v += bias[colc]; v = fmaxf(v, 0.f); }
        C[(size_t)row * 128 + colc] = v;
      }
    }
  }
}

// ---------------- attention logits: al_s[n,h] = sum_c xh[n,h,c]*att_s[h,c] ----------------
__global__ void att_logits_kernel(const float* __restrict__ xh,
                                  const float* __restrict__ att_s,
                                  const float* __restrict__ att_d,
                                  float* __restrict__ al_s, float* __restrict__ al_d, int n) {
  int t = blockIdx.x * blockDim.x + threadIdx.x;  // one per (node, head)
  if (t >= n * NHEAD) return;
  int head = t & 7;
  const float4* xr = (const float4*)(xh + (size_t)t * 16);
  const float4* as = (const float4*)(att_s + head * 16);
  const float4* ad = (const float4*)(att_d + head * 16);
  float ss = 0.f, dd = 0.f;
  #pragma unroll
  for (int i = 0; i < 4; i++) {
    float4 x = xr[i], a = as[i], b = ad[i];
    ss += x.x * a.x + x.y * a.y + x.z * a.z + x.w * a.w;
    dd += x.x * b.x + x.y * b.y + x.z * b.z + x.w * b.w;
  }
  al_s[t] = ss;
  al_d[t] = dd;
}

// ---------------- GAT aggregation: one wave per dst node, online softmax ----------------
// fused: softmax-weighted sum + gat bias + residual + LayerNorm + ReLU
__global__ __launch_bounds__(256) void gat_aggregate(
    const float* __restrict__ xh, const float* __restrict__ al_s,
    const float* __restrict__ al_d, const int* __restrict__ rowptr,
    const int* __restrict__ col, const float* __restrict__ h_res,
    const float* __restrict__ gb, const float* __restrict__ lng,
    const float* __restrict__ lnb, float* __restrict__ h_out, int n) {
  int lane = threadIdx.x & 63;
  int node = (blockIdx.x * blockDim.x + threadIdx.x) >> 6;
  if (node >= n) return;
  int head = lane >> 3;                 // 2 channels/lane -> head = (2*lane)/16
  const float2* xh2 = (const float2*)xh;
  float ald = al_d[node * NHEAD + head];
  int start = rowptr[node], end = rowptr[node + 1];
  float m = -INFINITY, denom = 0.f, acc0 = 0.f, acc1 = 0.f;
  for (int i = start; i <= end; ++i) {   // last iteration = self loop
    int s = (i < end) ? col[i] : node;
    float e = al_s[s * NHEAD + head] + ald;
    e = (e > 0.f) ? e : 0.2f * e;        // leaky_relu
    float mn = fmaxf(m, e);
    float scale = __expf(m - mn);        // exp(-inf)=0 on first iter
    float p = __expf(e - mn);
    float2 x = xh2[(size_t)s * 64 + lane];
    denom = denom * scale + p;
    acc0 = acc0 * scale + p * x.x;
    acc1 = acc1 * scale + p * x.y;
    m = mn;
  }
  float inv = 1.f / (denom + 1e-16f);
  int c0 = lane * 2, c1 = c0 + 1;
  float2 hr = ((const float2*)h_res)[(size_t)node * 64 + lane];
  float v0 = acc0 * inv + gb[c0] + hr.x;
  float v1 = acc1 * inv + gb[c1] + hr.y;
  // LayerNorm over 128 (wave reduction)
  float sum = v0 + v1;
  #pragma unroll
  for (int off = 32; off; off >>= 1) sum += __shfl_xor(sum, off);
  float mean = sum * (1.f / 128.f);
  float d0 = v0 - mean, d1 = v1 - mean;
  float sq = d0 * d0 + d1 * d1;
  #pragma unroll
  for (int off = 32; off; off >>= 1) sq += __shfl_xor(sq, off);
  float rstd = rsqrtf(sq * (1.f / 128.f) + 1e-5f);
  float o0 = fmaxf(d0 * rstd * lng[c0] + lnb[c0], 0.f);
  float o1 = fmaxf(d1 * rstd * lng[c1] + lnb[c1], 0.f);
  ((float2*)h_out)[(size_t)node * 64 + lane] = make_float2(o0, o1);
}

// ---------------- classifier: relu(h@w1+b1)@w2+b2, log_softmax ----------------
__global__ __launch_bounds__(256) void classifier_kernel(
    const float* __restrict__ h, const float* __restrict__ w1,
    const float* __restrict__ b1, const float* __restrict__ w2,
    const float* __restrict__ b2, float* __restrict__ out, int n) {
  __shared__ float s_w1[128 * 64];
  __shared__ float s_w2[64 * 16];
  __shared__ float s_b1[64];
  __shared__ float s_b2[16];
  __shared__ float s_hid[4][64];
  for (int i = threadIdx.x; i < 128 * 64; i += 256) s_w1[i] = w1[i];
  for (int i = threadIdx.x; i < 64 * 16; i += 256) s_w2[i] = w2[i];
  if (threadIdx.x < 64) s_b1[threadIdx.x] = b1[threadIdx.x];
  if (threadIdx.x < 16) s_b2[threadIdx.x] = b2[threadIdx.x];
  __syncthreads();
  int lane = threadIdx.x & 63;
  int w = threadIdx.x >> 6;
  int node = blockIdx.x * 4 + w;
  bool valid = node < n;
  const float* hr = h + (size_t)(valid ? node : 0) * 128;
  float acc = s_b1[lane];
  #pragma unroll 8
  for (int k = 0; k < 128; k++) acc = fmaf(hr[k], s_w1[k * 64 + lane], acc);
  acc = fmaxf(acc, 0.f);
  s_hid[w][lane] = acc;
  __syncthreads();
  int j = lane & 15;  // all lanes compute (4x redundant) so shuffles are uniform
  float logit = s_b2[j];
  #pragma unroll 8
  for (int k = 0; k < 64; k++) logit = fmaf(s_hid[w][k], s_w2[k * 16 + j], logit);
  float mx = logit;
  #pragma unroll
  for (int off = 8; off; off >>= 1) mx = fmaxf(mx, __shfl_xor(mx, off, 16));
  float ex = __expf(logit - mx);
  float se = ex;
  #pragma unroll
  for (int off = 8; off; off >>= 1) se += __shfl_xor(se, off, 16);
  if (valid && lane < 16) out[(size_t)node * 16 + lane] = logit - mx - __logf(se);
}

// ---------------- launch ----------------
extern "C" void kernel_launch(void* const* d_in, const int* in_sizes, int n_in,
                              void* d_out, int out_size, void* d_ws, size_t ws_size,
                              hipStream_t stream) {
  const float* x       = (const float*)d_in[0];
  const int*   ei      = (const int*)d_in[1];
  const float* proj_w  = (const float*)d_in[2];
  const float* proj_b  = (const float*)d_in[3];
  const float* lin_w   = (const float*)d_in[4];
  const float* att_src = (const float*)d_in[5];
  const float* att_dst = (const float*)d_in[6];
  const float* gat_b   = (const float*)d_in[7];
  const float* ln_g    = (const float*)d_in[8];
  const float* ln_b    = (const float*)d_in[9];
  const float* cls_w1  = (const float*)d_in[10];
  const float* cls_b1  = (const float*)d_in[11];
  const float* cls_w2  = (const float*)d_in[12];
  const float* cls_b2  = (const float*)d_in[13];
  float* outp = (float*)d_out;

  const int N = NN, E = EE;
  float* h0  = (float*)d_ws;
  float* h1  = h0 + (size_t)N * 128;
  float* xh  = h1 + (size_t)N * 128;
  float* als = xh + (size_t)N * 128;
  float* ald = als + (size_t)N * NHEAD;
  int* counts = (int*)(ald + (size_t)N * NHEAD);
  int* rowptr = counts + N;
  int* woff   = rowptr + N + 1;
  int* col    = woff + N;

  const int* e_src = ei;       // edge_index[0]
  const int* e_dst = ei + E;   // edge_index[1]

  // CSR by dst (rebuilt every call; inputs are restored each call)
  zero_ints<<<(N + 255) / 256, 256, 0, stream>>>(counts, N);
  hist_kernel<<<(E + 255) / 256, 256, 0, stream>>>(e_dst, counts, E);
  scan_kernel<<<1, 1024, 0, stream>>>(counts, rowptr, woff, N);
  scatter_kernel<<<(E + 255) / 256, 256, 0, stream>>>(e_src, e_dst, woff, col, E);

  // projection: h0 = relu(x @ proj_w + proj_b)
  gemm_n128<true><<<dim3((N + 63) / 64), 256, 0, stream>>>(x, proj_w, proj_b, h0, N, DIN);

  float* hc = h0;
  float* hn = h1;
  for (int l = 0; l < 3; ++l) {
    gemm_n128<false><<<dim3((N + 63) / 64), 256, 0, stream>>>(
        hc, lin_w + (size_t)l * 128 * 128, nullptr, xh, N, 128);
    att_logits_kernel<<<(N * NHEAD + 255) / 256, 256, 0, stream>>>(
        xh, att_src + l * 128, att_dst + l * 128, als, ald, N);
    gat_aggregate<<<(N + 3) / 4, 256, 0, stream>>>(
        xh, als, ald, rowptr, col, hc, gat_b + l * 128, ln_g + l * 128,
        ln_b + l * 128, hn, N);
    float* t = hc; hc = hn; hn = t;
  }
  classifier_kernel<<<(N + 3) / 4, 256, 0, stream>>>(hc, cls_w1, cls_b1, cls_w2, cls_b2, outp, N);
}

// Round 2
// 677.593 us; speedup vs baseline: 1.1372x; 1.1372x over previous
//
#include <hip/hip_runtime.h>
#include <hip/hip_bf16.h>
#include <math.h>

#define NN 50000
#define EE 500000
#define DIN 384
#define HIDD 128
#define NHEAD 8
#define OUTD 16

typedef __attribute__((ext_vector_type(8))) __bf16 bf16x8;
typedef __attribute__((ext_vector_type(4))) float f32x4;

__device__ __forceinline__ ushort f2bf(float f) {
  union { float f; unsigned u; } v; v.f = f;
  unsigned r = v.u + 0x7fffu + ((v.u >> 16) & 1u);
  return (ushort)(r >> 16);
}

// ---------------- CSR build ----------------
__global__ void zero_ints(int* p, int n) {
  int i = blockIdx.x * blockDim.x + threadIdx.x;
  if (i < n) p[i] = 0;
}

__global__ void hist_kernel(const int* __restrict__ dst, int* __restrict__ counts, int e) {
  int i = blockIdx.x * blockDim.x + threadIdx.x;
  if (i < e) atomicAdd(&counts[dst[i]], 1);
}

__global__ __launch_bounds__(1024) void scan_kernel(const int* __restrict__ counts,
                                                    int* __restrict__ rowptr,
                                                    int* __restrict__ woff, int n) {
  __shared__ int buf[1024];
  __shared__ int carry_s;
  if (threadIdx.x == 0) carry_s = 0;
  __syncthreads();
  for (int base = 0; base < n; base += 1024) {
    int i = base + threadIdx.x;
    int v = (i < n) ? counts[i] : 0;
    buf[threadIdx.x] = v;
    __syncthreads();
    #pragma unroll
    for (int off = 1; off < 1024; off <<= 1) {
      int t = (threadIdx.x >= off) ? buf[threadIdx.x - off] : 0;
      __syncthreads();
      buf[threadIdx.x] += t;
      __syncthreads();
    }
    int excl = buf[threadIdx.x] - v;
    if (i < n) { int r = carry_s + excl; rowptr[i] = r; woff[i] = r; }
    __syncthreads();
    if (threadIdx.x == 1023) carry_s += buf[1023];
    __syncthreads();
  }
  if (threadIdx.x == 0) rowptr[n] = carry_s;
}

__global__ void scatter_kernel(const int* __restrict__ src, const int* __restrict__ dst,
                               int* __restrict__ woff, int* __restrict__ col, int e) {
  int i = blockIdx.x * blockDim.x + threadIdx.x;
  if (i < e) {
    int p = atomicAdd(&woff[dst[i]], 1);
    col[p] = src[i];
  }
}

// ---------------- weight prep: wt = cast+transpose of proj_w / lin_w ----------------
// wt layout: [0 .. 49151]      proj_wt  [n=128][k=384]
//            [49152 + l*16384] lin_wt_l [n=128][k=128]
__global__ void prep_weights(const float* __restrict__ proj_w,
                             const float* __restrict__ lin_w,
                             ushort* __restrict__ wt) {
  int i = blockIdx.x * blockDim.x + threadIdx.x;
  if (i < 49152) {
    int k = i >> 7, n = i & 127;
    wt[n * 384 + k] = f2bf(proj_w[i]);
  } else if (i < 49152 + 3 * 16384) {
    int j = i - 49152;
    int l = j >> 14, rem = j & 16383;
    int k = rem >> 7, n = rem & 127;
    wt[49152 + l * 16384 + n * 128 + k] = f2bf(lin_w[j]);
  }
}

// ---------------- MFMA GEMM: C[M,128] = A[M,K] @ B[K,128] ----------------
// A fp32 row-major (cast to bf16 during staging); Bt bf16 [n=128][k=K].
// 128x128 block tile, 4 waves, each wave 64x64 via 4x4 mfma_f32_16x16x32_bf16.
#define LDS_STRIDE 72  // 64 + 8 pad: row stride 144 B = 36 dwords -> 2-way bank alias (free)
template<bool RELU_BIAS>
__global__ __launch_bounds__(256) void mfma_gemm_n128(const float* __restrict__ A,
                                                      const ushort* __restrict__ Bt,
                                                      const float* __restrict__ bias,
                                                      float* __restrict__ C, int M, int K) {
  __shared__ ushort sA[128 * LDS_STRIDE];
  __shared__ ushort sB[128 * LDS_STRIDE];
  const int tid = threadIdx.x;
  const int wave = tid >> 6, lane = tid & 63;
  const int q = lane >> 4, lm = lane & 15;
  const int wr = wave >> 1, wc = wave & 1;
  const int m0 = blockIdx.x * 128;

  f32x4 acc[4][4];
  #pragma unroll
  for (int i = 0; i < 4; i++)
    #pragma unroll
    for (int j = 0; j < 4; j++) acc[i][j] = {0.f, 0.f, 0.f, 0.f};

  for (int k0 = 0; k0 < K; k0 += 64) {
    __syncthreads();
    // stage A: 128 rows x 64 cols fp32 -> bf16 LDS
    #pragma unroll
    for (int p = 0; p < 8; ++p) {
      int idx = p * 256 + tid;       // one float4 each, 2048 total
      int r = idx >> 4;
      int c = (idx & 15) << 2;
      float4 v = make_float4(0.f, 0.f, 0.f, 0.f);
      if (m0 + r < M) v = *(const float4*)(A + (size_t)(m0 + r) * K + k0 + c);
      ushort4 u;
      u.x = f2bf(v.x); u.y = f2bf(v.y); u.z = f2bf(v.z); u.w = f2bf(v.w);
      *(ushort4*)&sA[r * LDS_STRIDE + c] = u;
    }
    // stage B: 128 rows x 64 cols bf16 (already [n][k])
    #pragma unroll
    for (int p = 0; p < 4; ++p) {
      int idx = p * 256 + tid;       // one 16B chunk each, 1024 total
      int r = idx >> 3;
      int c = (idx & 7) << 3;
      bf16x8 v = *(const bf16x8*)(Bt + (size_t)r * K + k0 + c);
      *(bf16x8*)&sB[r * LDS_STRIDE + c] = v;
    }
    __syncthreads();
    #pragma unroll
    for (int ks = 0; ks < 2; ++ks) {
      bf16x8 af[4], bfv[4];
      #pragma unroll
      for (int t = 0; t < 4; ++t) {
        af[t]  = *(const bf16x8*)&sA[(wr * 64 + t * 16 + lm) * LDS_STRIDE + ks * 32 + q * 8];
        bfv[t] = *(const bf16x8*)&sB[(wc * 64 + t * 16 + lm) * LDS_STRIDE + ks * 32 + q * 8];
      }
      #pragma unroll
      for (int i = 0; i < 4; ++i)
        #pragma unroll
        for (int j = 0; j < 4; ++j)
          acc[i][j] = __builtin_amdgcn_mfma_f32_16x16x32_bf16(af[i], bfv[j], acc[i][j], 0, 0, 0);
    }
  }
  // epilogue: C/D layout col=lane&15, row=(lane>>4)*4+reg  [m89-verified]
  #pragma unroll
  for (int i = 0; i < 4; ++i) {
    #pragma unroll
    for (int r = 0; r < 4; ++r) {
      int row = m0 + wr * 64 + i * 16 + q * 4 + r;
      if (row < M) {
        #pragma unroll
        for (int j = 0; j < 4; ++j) {
          int colc = wc * 64 + j * 16 + lm;
          float v = acc[i][j][r];
          if (RELU_BIAS) { v += bias[colc]; v = fmaxf(v, 0.f); }
          C[(size_t)row * 128 + colc] = v;
        }
      }
    }
  }
}

// ---------------- attention logits ----------------
__global__ void att_logits_kernel(const float* __restrict__ xh,
                                  const float* __restrict__ att_s,
                                  const float* __restrict__ att_d,
                                  float* __restrict__ al_s, float* __restrict__ al_d, int n) {
  int t = blockIdx.x * blockDim.x + threadIdx.x;
  if (t >= n * NHEAD) return;
  int head = t & 7;
  const float4* xr = (const float4*)(xh + (size_t)t * 16);
  const float4* as = (const float4*)(att_s + head * 16);
  const float4* ad = (const float4*)(att_d + head * 16);
  float ss = 0.f, dd = 0.f;
  #pragma unroll
  for (int i = 0; i < 4; i++) {
    float4 x = xr[i], a = as[i], b = ad[i];
    ss += x.x * a.x + x.y * a.y + x.z * a.z + x.w * a.w;
    dd += x.x * b.x + x.y * b.y + x.z * b.z + x.w * b.w;
  }
  al_s[t] = ss;
  al_d[t] = dd;
}

// ---------------- GAT aggregation (one wave per dst node, online softmax) ----------------
__global__ __launch_bounds__(256) void gat_aggregate(
    const float* __restrict__ xh, const float* __restrict__ al_s,
    const float* __restrict__ al_d, const int* __restrict__ rowptr,
    const int* __restrict__ col, const float* __restrict__ h_res,
    const float* __restrict__ gb, const float* __restrict__ lng,
    const float* __restrict__ lnb, float* __restrict__ h_out, int n) {
  int lane = threadIdx.x & 63;
  int node = (blockIdx.x * blockDim.x + threadIdx.x) >> 6;
  if (node >= n) return;
  int head = lane >> 3;
  const float2* xh2 = (const float2*)xh;
  float ald = al_d[node * NHEAD + head];
  int start = rowptr[node], end = rowptr[node + 1];
  float m = -INFINITY, denom = 0.f, acc0 = 0.f, acc1 = 0.f;
  for (int i = start; i <= end; ++i) {   // last iteration = self loop
    int s = (i < end) ? col[i] : node;
    float e = al_s[s * NHEAD + head] + ald;
    e = (e > 0.f) ? e : 0.2f * e;
    float mn = fmaxf(m, e);
    float scale = __expf(m - mn);
    float p = __expf(e - mn);
    float2 x = xh2[(size_t)s * 64 + lane];
    denom = denom * scale + p;
    acc0 = acc0 * scale + p * x.x;
    acc1 = acc1 * scale + p * x.y;
    m = mn;
  }
  float inv = 1.f / (denom + 1e-16f);
  int c0 = lane * 2, c1 = c0 + 1;
  float2 hr = ((const float2*)h_res)[(size_t)node * 64 + lane];
  float v0 = acc0 * inv + gb[c0] + hr.x;
  float v1 = acc1 * inv + gb[c1] + hr.y;
  float sum = v0 + v1;
  #pragma unroll
  for (int off = 32; off; off >>= 1) sum += __shfl_xor(sum, off);
  float mean = sum * (1.f / 128.f);
  float d0 = v0 - mean, d1 = v1 - mean;
  float sq = d0 * d0 + d1 * d1;
  #pragma unroll
  for (int off = 32; off; off >>= 1) sq += __shfl_xor(sq, off);
  float rstd = rsqrtf(sq * (1.f / 128.f) + 1e-5f);
  float o0 = fmaxf(d0 * rstd * lng[c0] + lnb[c0], 0.f);
  float o1 = fmaxf(d1 * rstd * lng[c1] + lnb[c1], 0.f);
  ((float2*)h_out)[(size_t)node * 64 + lane] = make_float2(o0, o1);
}

// ---------------- classifier ----------------
__global__ __launch_bounds__(256) void classifier_kernel(
    const float* __restrict__ h, const float* __restrict__ w1,
    const float* __restrict__ b1, const float* __restrict__ w2,
    const float* __restrict__ b2, float* __restrict__ out, int n) {
  __shared__ float s_w1[128 * 64];
  __shared__ float s_w2[64 * 16];
  __shared__ float s_b1[64];
  __shared__ float s_b2[16];
  __shared__ float s_hid[4][64];
  for (int i = threadIdx.x; i < 128 * 64; i += 256) s_w1[i] = w1[i];
  for (int i = threadIdx.x; i < 64 * 16; i += 256) s_w2[i] = w2[i];
  if (threadIdx.x < 64) s_b1[threadIdx.x] = b1[threadIdx.x];
  if (threadIdx.x < 16) s_b2[threadIdx.x] = b2[threadIdx.x];
  __syncthreads();
  int lane = threadIdx.x & 63;
  int w = threadIdx.x >> 6;
  int node = blockIdx.x * 4 + w;
  bool valid = node < n;
  const float* hr = h + (size_t)(valid ? node : 0) * 128;
  float acc = s_b1[lane];
  #pragma unroll 8
  for (int k = 0; k < 128; k++) acc = fmaf(hr[k], s_w1[k * 64 + lane], acc);
  acc = fmaxf(acc, 0.f);
  s_hid[w][lane] = acc;
  __syncthreads();
  int j = lane & 15;
  float logit = s_b2[j];
  #pragma unroll 8
  for (int k = 0; k < 64; k++) logit = fmaf(s_hid[w][k], s_w2[k * 16 + j], logit);
  float mx = logit;
  #pragma unroll
  for (int off = 8; off; off >>= 1) mx = fmaxf(mx, __shfl_xor(mx, off, 16));
  float ex = __expf(logit - mx);
  float se = ex;
  #pragma unroll
  for (int off = 8; off; off >>= 1) se += __shfl_xor(se, off, 16);
  if (valid && lane < 16) out[(size_t)node * 16 + lane] = logit - mx - __logf(se);
}

// ---------------- launch ----------------
extern "C" void kernel_launch(void* const* d_in, const int* in_sizes, int n_in,
                              void* d_out, int out_size, void* d_ws, size_t ws_size,
                              hipStream_t stream) {
  const float* x       = (const float*)d_in[0];
  const int*   ei      = (const int*)d_in[1];
  const float* proj_w  = (const float*)d_in[2];
  const float* proj_b  = (const float*)d_in[3];
  const float* lin_w   = (const float*)d_in[4];
  const float* att_src = (const float*)d_in[5];
  const float* att_dst = (const float*)d_in[6];
  const float* gat_b   = (const float*)d_in[7];
  const float* ln_g    = (const float*)d_in[8];
  const float* ln_b    = (const float*)d_in[9];
  const float* cls_w1  = (const float*)d_in[10];
  const float* cls_b1  = (const float*)d_in[11];
  const float* cls_w2  = (const float*)d_in[12];
  const float* cls_b2  = (const float*)d_in[13];
  float* outp = (float*)d_out;

  const int N = NN, E = EE;
  // workspace layout (wt first to keep 16B alignment simple)
  ushort* wt  = (ushort*)d_ws;                      // 98304 ushort = 49152 floats
  float* h0   = (float*)d_ws + 49152;
  float* h1   = h0 + (size_t)N * 128;
  float* xh   = h1 + (size_t)N * 128;
  float* als  = xh + (size_t)N * 128;
  float* ald  = als + (size_t)N * NHEAD;
  int* counts = (int*)(ald + (size_t)N * NHEAD);
  int* rowptr = counts + N;
  int* woff   = rowptr + N + 1;
  int* col    = woff + N;

  const int* e_src = ei;
  const int* e_dst = ei + E;

  prep_weights<<<(49152 + 3 * 16384 + 255) / 256, 256, 0, stream>>>(proj_w, lin_w, wt);

  zero_ints<<<(N + 255) / 256, 256, 0, stream>>>(counts, N);
  hist_kernel<<<(E + 255) / 256, 256, 0, stream>>>(e_dst, counts, E);
  scan_kernel<<<1, 1024, 0, stream>>>(counts, rowptr, woff, N);
  scatter_kernel<<<(E + 255) / 256, 256, 0, stream>>>(e_src, e_dst, woff, col, E);

  const int gblocks = (N + 127) / 128;
  // projection: h0 = relu(x @ proj_w + proj_b)
  mfma_gemm_n128<true><<<gblocks, 256, 0, stream>>>(x, wt, proj_b, h0, N, DIN);

  float* hc = h0;
  float* hn = h1;
  for (int l = 0; l < 3; ++l) {
    mfma_gemm_n128<false><<<gblocks, 256, 0, stream>>>(
        hc, wt + 49152 + l * 16384, nullptr, xh, N, 128);
    att_logits_kernel<<<(N * NHEAD + 255) / 256, 256, 0, stream>>>(
        xh, att_src + l * 128, att_dst + l * 128, als, ald, N);
    gat_aggregate<<<(N + 3) / 4, 256, 0, stream>>>(
        xh, als, ald, rowptr, col, hc, gat_b + l * 128, ln_g + l * 128,
        ln_b + l * 128, hn, N);
    float* t = hc; hc = hn; hn = t;
  }
  classifier_kernel<<<(N + 3) / 4, 256, 0, stream>>>(hc, cls_w1, cls_b1, cls_w2, cls_b2, outp, N);
}

// Round 3
// 675.201 us; speedup vs baseline: 1.1412x; 1.0035x over previous
//
#include <hip/hip_runtime.h>
#include <hip/hip_bf16.h>
#include <math.h>

#define NN 50000
#define EE 500000
#define DIN 384
#define HIDD 128
#define NHEAD 8
#define OUTD 16

typedef __attribute__((ext_vector_type(8))) __bf16 bf16x8;
typedef __attribute__((ext_vector_type(4))) float f32x4;

__device__ __forceinline__ ushort f2bf(float f) {
  union { float f; unsigned u; } v; v.f = f;
  unsigned r = v.u + 0x7fffu + ((v.u >> 16) & 1u);
  return (ushort)(r >> 16);
}

// ---------------- CSR build ----------------
__global__ void zero_ints(int* p, int n) {
  int i = blockIdx.x * blockDim.x + threadIdx.x;
  if (i < n) p[i] = 0;
}

__global__ void hist_kernel(const int* __restrict__ dst, int* __restrict__ counts, int e) {
  int i = blockIdx.x * blockDim.x + threadIdx.x;
  if (i < e) atomicAdd(&counts[dst[i]], 1);
}

// single-block scan, thread-local contiguous chunks: ~20 barriers total
__global__ __launch_bounds__(1024) void scan_kernel(const int* __restrict__ counts,
                                                    int* __restrict__ rowptr,
                                                    int* __restrict__ woff, int n) {
  __shared__ int tsum[1024];
  const int t = threadIdx.x;
  const int chunk = (n + 1023) / 1024;
  const int lo = t * chunk;
  const int hi = min(lo + chunk, n);
  int s = 0;
  for (int i = lo; i < hi; ++i) s += counts[i];
  tsum[t] = s;
  __syncthreads();
  #pragma unroll
  for (int off = 1; off < 1024; off <<= 1) {
    int v = (t >= off) ? tsum[t - off] : 0;
    __syncthreads();
    tsum[t] += v;
    __syncthreads();
  }
  int run = tsum[t] - s;  // exclusive prefix of this chunk
  for (int i = lo; i < hi; ++i) {
    rowptr[i] = run; woff[i] = run;
    run += counts[i];
  }
  if (t == 1023) rowptr[n] = tsum[1023];
}

__global__ void scatter_kernel(const int* __restrict__ src, const int* __restrict__ dst,
                               int* __restrict__ woff, int* __restrict__ col, int e) {
  int i = blockIdx.x * blockDim.x + threadIdx.x;
  if (i < e) {
    int p = atomicAdd(&woff[dst[i]], 1);
    col[p] = src[i];
  }
}

// ---------------- weight prep: wt = cast+transpose of proj_w / lin_w ----------------
__global__ void prep_weights(const float* __restrict__ proj_w,
                             const float* __restrict__ lin_w,
                             ushort* __restrict__ wt) {
  int i = blockIdx.x * blockDim.x + threadIdx.x;
  if (i < 49152) {
    int k = i >> 7, n = i & 127;
    wt[n * 384 + k] = f2bf(proj_w[i]);
  } else if (i < 49152 + 3 * 16384) {
    int j = i - 49152;
    int l = j >> 14, rem = j & 16383;
    int k = rem >> 7, n = rem & 127;
    wt[49152 + l * 16384 + n * 128 + k] = f2bf(lin_w[j]);
  }
}

// ---------------- MFMA GEMM: C[M,128] = A[M,K] @ B[K,128] ----------------
#define LDS_STRIDE 72  // 64 + 8 pad: 144 B row stride -> 2-way bank alias (free, m136)
template<bool RELU_BIAS>
__global__ __launch_bounds__(256) void mfma_gemm_n128(const float* __restrict__ A,
                                                      const ushort* __restrict__ Bt,
                                                      const float* __restrict__ bias,
                                                      float* __restrict__ C, int M, int K) {
  __shared__ ushort sA[128 * LDS_STRIDE];
  __shared__ ushort sB[128 * LDS_STRIDE];
  const int tid = threadIdx.x;
  const int wave = tid >> 6, lane = tid & 63;
  const int q = lane >> 4, lm = lane & 15;
  const int wr = wave >> 1, wc = wave & 1;
  const int m0 = blockIdx.x * 128;

  f32x4 acc[4][4];
  #pragma unroll
  for (int i = 0; i < 4; i++)
    #pragma unroll
    for (int j = 0; j < 4; j++) acc[i][j] = {0.f, 0.f, 0.f, 0.f};

  for (int k0 = 0; k0 < K; k0 += 64) {
    __syncthreads();
    #pragma unroll
    for (int p = 0; p < 8; ++p) {
      int idx = p * 256 + tid;
      int r = idx >> 4;
      int c = (idx & 15) << 2;
      float4 v = make_float4(0.f, 0.f, 0.f, 0.f);
      if (m0 + r < M) v = *(const float4*)(A + (size_t)(m0 + r) * K + k0 + c);
      ushort4 u;
      u.x = f2bf(v.x); u.y = f2bf(v.y); u.z = f2bf(v.z); u.w = f2bf(v.w);
      *(ushort4*)&sA[r * LDS_STRIDE + c] = u;
    }
    #pragma unroll
    for (int p = 0; p < 4; ++p) {
      int idx = p * 256 + tid;
      int r = idx >> 3;
      int c = (idx & 7) << 3;
      bf16x8 v = *(const bf16x8*)(Bt + (size_t)r * K + k0 + c);
      *(bf16x8*)&sB[r * LDS_STRIDE + c] = v;
    }
    __syncthreads();
    #pragma unroll
    for (int ks = 0; ks < 2; ++ks) {
      bf16x8 af[4], bfv[4];
      #pragma unroll
      for (int t = 0; t < 4; ++t) {
        af[t]  = *(const bf16x8*)&sA[(wr * 64 + t * 16 + lm) * LDS_STRIDE + ks * 32 + q * 8];
        bfv[t] = *(const bf16x8*)&sB[(wc * 64 + t * 16 + lm) * LDS_STRIDE + ks * 32 + q * 8];
      }
      #pragma unroll
      for (int i = 0; i < 4; ++i)
        #pragma unroll
        for (int j = 0; j < 4; ++j)
          acc[i][j] = __builtin_amdgcn_mfma_f32_16x16x32_bf16(af[i], bfv[j], acc[i][j], 0, 0, 0);
    }
  }
  #pragma unroll
  for (int i = 0; i < 4; ++i) {
    #pragma unroll
    for (int r = 0; r < 4; ++r) {
      int row = m0 + wr * 64 + i * 16 + q * 4 + r;
      if (row < M) {
        #pragma unroll
        for (int j = 0; j < 4; ++j) {
          int colc = wc * 64 + j * 16 + lm;
          float v = acc[i][j][r];
          if (RELU_BIAS) { v += bias[colc]; v = fmaxf(v, 0.f); }
          C[(size_t)row * 128 + colc] = v;
        }
      }
    }
  }
}

// ---------------- attention logits ----------------
__global__ void att_logits_kernel(const float* __restrict__ xh,
                                  const float* __restrict__ att_s,
                                  const float* __restrict__ att_d,
                                  float* __restrict__ al_s, float* __restrict__ al_d, int n) {
  int t = blockIdx.x * blockDim.x + threadIdx.x;
  if (t >= n * NHEAD) return;
  int head = t & 7;
  const float4* xr = (const float4*)(xh + (size_t)t * 16);
  const float4* as = (const float4*)(att_s + head * 16);
  const float4* ad = (const float4*)(att_d + head * 16);
  float ss = 0.f, dd = 0.f;
  #pragma unroll
  for (int i = 0; i < 4; i++) {
    float4 x = xr[i], a = as[i], b = ad[i];
    ss += x.x * a.x + x.y * a.y + x.z * a.z + x.w * a.w;
    dd += x.x * b.x + x.y * b.y + x.z * b.z + x.w * b.w;
  }
  al_s[t] = ss;
  al_d[t] = dd;
}

// ---------------- GAT aggregation: one wave per node, online softmax, 1-deep prefetch ----
__global__ __launch_bounds__(256) void gat_aggregate(
    const float* __restrict__ xh, const float* __restrict__ al_s,
    const float* __restrict__ al_d, const int* __restrict__ rowptr,
    const int* __restrict__ col, const float* __restrict__ h_res,
    const float* __restrict__ gb, const float* __restrict__ lng,
    const float* __restrict__ lnb, float* __restrict__ h_out, int n) {
  int lane = threadIdx.x & 63;
  int node = (blockIdx.x * blockDim.x + threadIdx.x) >> 6;
  if (node >= n) return;
  int head = lane >> 3;
  const float2* xh2 = (const float2*)xh;
  float ald = al_d[node * NHEAD + head];
  int start = rowptr[node], end = rowptr[node + 1];
  // prefetch pipeline: loads for iteration i+1 issue before the compute of i
  int sP = (start < end) ? col[start] : node;
  float eP = al_s[sP * NHEAD + head];
  float2 xP = xh2[(size_t)sP * 64 + lane];
  float m = -INFINITY, denom = 0.f, acc0 = 0.f, acc1 = 0.f;
  for (int i = start; i <= end; ++i) {   // last iteration = self loop
    float e = eP + ald;
    float2 x = xP;
    int i2 = i + 1;
    if (i2 <= end) {
      int s2 = (i2 < end) ? col[i2] : node;
      eP = al_s[s2 * NHEAD + head];
      xP = xh2[(size_t)s2 * 64 + lane];
    }
    e = (e > 0.f) ? e : 0.2f * e;
    float mn = fmaxf(m, e);
    float scale = __expf(m - mn);
    float p = __expf(e - mn);
    denom = denom * scale + p;
    acc0 = acc0 * scale + p * x.x;
    acc1 = acc1 * scale + p * x.y;
    m = mn;
  }
  float inv = 1.f / (denom + 1e-16f);
  int c0 = lane * 2, c1 = c0 + 1;
  float2 hr = ((const float2*)h_res)[(size_t)node * 64 + lane];
  float v0 = acc0 * inv + gb[c0] + hr.x;
  float v1 = acc1 * inv + gb[c1] + hr.y;
  float sum = v0 + v1;
  #pragma unroll
  for (int off = 32; off; off >>= 1) sum += __shfl_xor(sum, off);
  float mean = sum * (1.f / 128.f);
  float d0 = v0 - mean, d1 = v1 - mean;
  float sq = d0 * d0 + d1 * d1;
  #pragma unroll
  for (int off = 32; off; off >>= 1) sq += __shfl_xor(sq, off);
  float rstd = rsqrtf(sq * (1.f / 128.f) + 1e-5f);
  float o0 = fmaxf(d0 * rstd * lng[c0] + lnb[c0], 0.f);
  float o1 = fmaxf(d1 * rstd * lng[c1] + lnb[c1], 0.f);
  ((float2*)h_out)[(size_t)node * 64 + lane] = make_float2(o0, o1);
}

// ---------------- classifier: grid-stride, weights staged once per block ----------------
#define CLS_BLOCKS 625
__global__ __launch_bounds__(256) void classifier_kernel(
    const float* __restrict__ h, const float* __restrict__ w1,
    const float* __restrict__ b1, const float* __restrict__ w2,
    const float* __restrict__ b2, float* __restrict__ out, int n) {
  __shared__ float s_w1[128 * 64];
  __shared__ float s_w2[64 * 16];
  __shared__ float s_b1[64];
  __shared__ float s_b2[16];
  __shared__ float s_hid[4][64];  // per-wave private row -> no in-loop barrier
  for (int i = threadIdx.x; i < 128 * 64; i += 256) s_w1[i] = w1[i];
  for (int i = threadIdx.x; i < 64 * 16; i += 256) s_w2[i] = w2[i];
  if (threadIdx.x < 64) s_b1[threadIdx.x] = b1[threadIdx.x];
  if (threadIdx.x < 16) s_b2[threadIdx.x] = b2[threadIdx.x];
  __syncthreads();
  const int lane = threadIdx.x & 63;
  const int w = threadIdx.x >> 6;
  const int j = lane & 15;
  for (int node = blockIdx.x * 4 + w; node < n; node += CLS_BLOCKS * 4) {
    const float4* hr = (const float4*)(h + (size_t)node * 128);
    float acc = s_b1[lane];
    #pragma unroll
    for (int k4 = 0; k4 < 32; ++k4) {
      float4 hv = hr[k4];               // wave-uniform 16B broadcast
      acc = fmaf(hv.x, s_w1[(k4 * 4 + 0) * 64 + lane], acc);
      acc = fmaf(hv.y, s_w1[(k4 * 4 + 1) * 64 + lane], acc);
      acc = fmaf(hv.z, s_w1[(k4 * 4 + 2) * 64 + lane], acc);
      acc = fmaf(hv.w, s_w1[(k4 * 4 + 3) * 64 + lane], acc);
    }
    acc = fmaxf(acc, 0.f);
    s_hid[w][lane] = acc;               // same-wave write->read: compiler inserts lgkmcnt
    float logit = s_b2[j];              // 4x redundant over lane groups, keeps shuffles uniform
    #pragma unroll
    for (int k = 0; k < 64; ++k) logit = fmaf(s_hid[w][k], s_w2[k * 16 + j], logit);
    float mx = logit;
    #pragma unroll
    for (int off = 8; off; off >>= 1) mx = fmaxf(mx, __shfl_xor(mx, off, 16));
    float ex = __expf(logit - mx);
    float se = ex;
    #pragma unroll
    for (int off = 8; off; off >>= 1) se += __shfl_xor(se, off, 16);
    if (lane < 16) out[(size_t)node * 16 + lane] = logit - mx - __logf(se);
  }
}

// ---------------- launch ----------------
extern "C" void kernel_launch(void* const* d_in, const int* in_sizes, int n_in,
                              void* d_out, int out_size, void* d_ws, size_t ws_size,
                              hipStream_t stream) {
  const float* x       = (const float*)d_in[0];
  const int*   ei      = (const int*)d_in[1];
  const float* proj_w  = (const float*)d_in[2];
  const float* proj_b  = (const float*)d_in[3];
  const float* lin_w   = (const float*)d_in[4];
  const float* att_src = (const float*)d_in[5];
  const float* att_dst = (const float*)d_in[6];
  const float* gat_b   = (const float*)d_in[7];
  const float* ln_g    = (const float*)d_in[8];
  const float* ln_b    = (const float*)d_in[9];
  const float* cls_w1  = (const float*)d_in[10];
  const float* cls_b1  = (const float*)d_in[11];
  const float* cls_w2  = (const float*)d_in[12];
  const float* cls_b2  = (const float*)d_in[13];
  float* outp = (float*)d_out;

  const int N = NN, E = EE;
  ushort* wt  = (ushort*)d_ws;
  float* h0   = (float*)d_ws + 49152;
  float* h1   = h0 + (size_t)N * 128;
  float* xh   = h1 + (size_t)N * 128;
  float* als  = xh + (size_t)N * 128;
  float* ald  = als + (size_t)N * NHEAD;
  int* counts = (int*)(ald + (size_t)N * NHEAD);
  int* rowptr = counts + N;
  int* woff   = rowptr + N + 1;
  int* col    = woff + N;

  const int* e_src = ei;
  const int* e_dst = ei + E;

  prep_weights<<<(49152 + 3 * 16384 + 255) / 256, 256, 0, stream>>>(proj_w, lin_w, wt);

  zero_ints<<<(N + 255) / 256, 256, 0, stream>>>(counts, N);
  hist_kernel<<<(E + 255) / 256, 256, 0, stream>>>(e_dst, counts, E);
  scan_kernel<<<1, 1024, 0, stream>>>(counts, rowptr, woff, N);
  scatter_kernel<<<(E + 255) / 256, 256, 0, stream>>>(e_src, e_dst, woff, col, E);

  const int gblocks = (N + 127) / 128;
  mfma_gemm_n128<true><<<gblocks, 256, 0, stream>>>(x, wt, proj_b, h0, N, DIN);

  float* hc = h0;
  float* hn = h1;
  for (int l = 0; l < 3; ++l) {
    mfma_gemm_n128<false><<<gblocks, 256, 0, stream>>>(
        hc, wt + 49152 + l * 16384, nullptr, xh, N, 128);
    att_logits_kernel<<<(N * NHEAD + 255) / 256, 256, 0, stream>>>(
        xh, att_src + l * 128, att_dst + l * 128, als, ald, N);
    gat_aggregate<<<(N + 3) / 4, 256, 0, stream>>>(
        xh, als, ald, rowptr, col, hc, gat_b + l * 128, ln_g + l * 128,
        ln_b + l * 128, hn, N);
    float* t = hc; hc = hn; hn = t;
  }
  classifier_kernel<<<CLS_BLOCKS, 256, 0, stream>>>(hc, cls_w1, cls_b1, cls_w2, cls_b2, outp, N);
}

// Round 4
// 578.965 us; speedup vs baseline: 1.3309x; 1.1662x over previous
//
#include <hip/hip_runtime.h>
#include <hip/hip_bf16.h>
#include <math.h>

#define NN 50000
#define EE 500000
#define DIN 384
#define HIDD 128
#define NHEAD 8
#define OUTD 16

typedef __attribute__((ext_vector_type(8))) __bf16 bf16x8;
typedef __attribute__((ext_vector_type(4))) float f32x4;

__device__ __forceinline__ ushort f2bf(float f) {
  union { float f; unsigned u; } v; v.f = f;
  unsigned r = v.u + 0x7fffu + ((v.u >> 16) & 1u);
  return (ushort)(r >> 16);
}

// ---------------- CSR build ----------------
__global__ void zero_ints(int* p, int n) {
  int i = blockIdx.x * blockDim.x + threadIdx.x;
  if (i < n) p[i] = 0;
}

__global__ void hist_kernel(const int* __restrict__ dst, int* __restrict__ counts, int e) {
  int i = blockIdx.x * blockDim.x + threadIdx.x;
  if (i < e) atomicAdd(&counts[dst[i]], 1);
}

// ---- hierarchical scan: 196 blocks of 256, all passes coalesced ----
#define SCAN_BS 256
#define SCAN_NBLK ((NN + SCAN_BS - 1) / SCAN_BS)  // 196

__global__ __launch_bounds__(256) void partial_sums(const int* __restrict__ counts,
                                                    int* __restrict__ bsum, int n) {
  __shared__ int red[256];
  int i = blockIdx.x * 256 + threadIdx.x;
  red[threadIdx.x] = (i < n) ? counts[i] : 0;
  __syncthreads();
  #pragma unroll
  for (int off = 128; off; off >>= 1) {
    if (threadIdx.x < off) red[threadIdx.x] += red[threadIdx.x + off];
    __syncthreads();
  }
  if (threadIdx.x == 0) bsum[blockIdx.x] = red[0];
}

__global__ __launch_bounds__(256) void scan_bsums(const int* __restrict__ bsum,
                                                  int* __restrict__ boff, int nb) {
  __shared__ int buf[256];
  int t = threadIdx.x;
  int v = (t < nb) ? bsum[t] : 0;
  buf[t] = v;
  __syncthreads();
  #pragma unroll
  for (int off = 1; off < 256; off <<= 1) {
    int u = (t >= off) ? buf[t - off] : 0;
    __syncthreads();
    buf[t] += u;
    __syncthreads();
  }
  if (t < nb) boff[t] = buf[t] - v;  // exclusive prefix of block sums
}

__global__ __launch_bounds__(256) void final_scan(const int* __restrict__ counts,
                                                  const int* __restrict__ boff,
                                                  int* __restrict__ rowptr,
                                                  int* __restrict__ woff, int n) {
  __shared__ int buf[256];
  int i = blockIdx.x * 256 + threadIdx.x;
  int t = threadIdx.x;
  int v = (i < n) ? counts[i] : 0;
  buf[t] = v;
  __syncthreads();
  #pragma unroll
  for (int off = 1; off < 256; off <<= 1) {
    int u = (t >= off) ? buf[t - off] : 0;
    __syncthreads();
    buf[t] += u;
    __syncthreads();
  }
  int excl = boff[blockIdx.x] + buf[t] - v;
  if (i < n) { rowptr[i] = excl; woff[i] = excl; }
  if (i == n - 1) rowptr[n] = excl + v;
}

__global__ void scatter_kernel(const int* __restrict__ src, const int* __restrict__ dst,
                               int* __restrict__ woff, int* __restrict__ col, int e) {
  int i = blockIdx.x * blockDim.x + threadIdx.x;
  if (i < e) {
    int p = atomicAdd(&woff[dst[i]], 1);
    col[p] = src[i];
  }
}

// ---------------- weight prep ----------------
__global__ void prep_weights(const float* __restrict__ proj_w,
                             const float* __restrict__ lin_w,
                             ushort* __restrict__ wt) {
  int i = blockIdx.x * blockDim.x + threadIdx.x;
  if (i < 49152) {
    int k = i >> 7, n = i & 127;
    wt[n * 384 + k] = f2bf(proj_w[i]);
  } else if (i < 49152 + 3 * 16384) {
    int j = i - 49152;
    int l = j >> 14, rem = j & 16383;
    int k = rem >> 7, n = rem & 127;
    wt[49152 + l * 16384 + n * 128 + k] = f2bf(lin_w[j]);
  }
}

// ---------------- MFMA GEMM: C[M,128] = A[M,K] @ B[K,128] ----------------
#define LDS_STRIDE 72  // 64 + 8 pad: 144 B row stride -> 2-way bank alias (free, m136)
template<bool RELU_BIAS>
__global__ __launch_bounds__(256) void mfma_gemm_n128(const float* __restrict__ A,
                                                      const ushort* __restrict__ Bt,
                                                      const float* __restrict__ bias,
                                                      float* __restrict__ C, int M, int K) {
  __shared__ ushort sA[128 * LDS_STRIDE];
  __shared__ ushort sB[128 * LDS_STRIDE];
  const int tid = threadIdx.x;
  const int wave = tid >> 6, lane = tid & 63;
  const int q = lane >> 4, lm = lane & 15;
  const int wr = wave >> 1, wc = wave & 1;
  const int m0 = blockIdx.x * 128;

  f32x4 acc[4][4];
  #pragma unroll
  for (int i = 0; i < 4; i++)
    #pragma unroll
    for (int j = 0; j < 4; j++) acc[i][j] = {0.f, 0.f, 0.f, 0.f};

  for (int k0 = 0; k0 < K; k0 += 64) {
    __syncthreads();
    #pragma unroll
    for (int p = 0; p < 8; ++p) {
      int idx = p * 256 + tid;
      int r = idx >> 4;
      int c = (idx & 15) << 2;
      float4 v = make_float4(0.f, 0.f, 0.f, 0.f);
      if (m0 + r < M) v = *(const float4*)(A + (size_t)(m0 + r) * K + k0 + c);
      ushort4 u;
      u.x = f2bf(v.x); u.y = f2bf(v.y); u.z = f2bf(v.z); u.w = f2bf(v.w);
      *(ushort4*)&sA[r * LDS_STRIDE + c] = u;
    }
    #pragma unroll
    for (int p = 0; p < 4; ++p) {
      int idx = p * 256 + tid;
      int r = idx >> 3;
      int c = (idx & 7) << 3;
      bf16x8 v = *(const bf16x8*)(Bt + (size_t)r * K + k0 + c);
      *(bf16x8*)&sB[r * LDS_STRIDE + c] = v;
    }
    __syncthreads();
    #pragma unroll
    for (int ks = 0; ks < 2; ++ks) {
      bf16x8 af[4], bfv[4];
      #pragma unroll
      for (int t = 0; t < 4; ++t) {
        af[t]  = *(const bf16x8*)&sA[(wr * 64 + t * 16 + lm) * LDS_STRIDE + ks * 32 + q * 8];
        bfv[t] = *(const bf16x8*)&sB[(wc * 64 + t * 16 + lm) * LDS_STRIDE + ks * 32 + q * 8];
      }
      #pragma unroll
      for (int i = 0; i < 4; ++i)
        #pragma unroll
        for (int j = 0; j < 4; ++j)
          acc[i][j] = __builtin_amdgcn_mfma_f32_16x16x32_bf16(af[i], bfv[j], acc[i][j], 0, 0, 0);
    }
  }
  #pragma unroll
  for (int i = 0; i < 4; ++i) {
    #pragma unroll
    for (int r = 0; r < 4; ++r) {
      int row = m0 + wr * 64 + i * 16 + q * 4 + r;
      if (row < M) {
        #pragma unroll
        for (int j = 0; j < 4; ++j) {
          int colc = wc * 64 + j * 16 + lm;
          float v = acc[i][j][r];
          if (RELU_BIAS) { v += bias[colc]; v = fmaxf(v, 0.f); }
          C[(size_t)row * 128 + colc] = v;
        }
      }
    }
  }
}

// ---------------- attention logits ----------------
__global__ void att_logits_kernel(const float* __restrict__ xh,
                                  const float* __restrict__ att_s,
                                  const float* __restrict__ att_d,
                                  float* __restrict__ al_s, float* __restrict__ al_d, int n) {
  int t = blockIdx.x * blockDim.x + threadIdx.x;
  if (t >= n * NHEAD) return;
  int head = t & 7;
  const float4* xr = (const float4*)(xh + (size_t)t * 16);
  const float4* as = (const float4*)(att_s + head * 16);
  const float4* ad = (const float4*)(att_d + head * 16);
  float ss = 0.f, dd = 0.f;
  #pragma unroll
  for (int i = 0; i < 4; i++) {
    float4 x = xr[i], a = as[i], b = ad[i];
    ss += x.x * a.x + x.y * a.y + x.z * a.z + x.w * a.w;
    dd += x.x * b.x + x.y * b.y + x.z * b.z + x.w * b.w;
  }
  al_s[t] = ss;
  al_d[t] = dd;
}

// ---------------- GAT aggregation: one wave per node, online softmax, 1-deep prefetch ----
__global__ __launch_bounds__(256) void gat_aggregate(
    const float* __restrict__ xh, const float* __restrict__ al_s,
    const float* __restrict__ al_d, const int* __restrict__ rowptr,
    const int* __restrict__ col, const float* __restrict__ h_res,
    const float* __restrict__ gb, const float* __restrict__ lng,
    const float* __restrict__ lnb, float* __restrict__ h_out, int n) {
  int lane = threadIdx.x & 63;
  int node = (blockIdx.x * blockDim.x + threadIdx.x) >> 6;
  if (node >= n) return;
  int head = lane >> 3;
  const float2* xh2 = (const float2*)xh;
  float ald = al_d[node * NHEAD + head];
  int start = rowptr[node], end = rowptr[node + 1];
  int sP = (start < end) ? col[start] : node;
  float eP = al_s[sP * NHEAD + head];
  float2 xP = xh2[(size_t)sP * 64 + lane];
  float m = -INFINITY, denom = 0.f, acc0 = 0.f, acc1 = 0.f;
  for (int i = start; i <= end; ++i) {   // last iteration = self loop
    float e = eP + ald;
    float2 x = xP;
    int i2 = i + 1;
    if (i2 <= end) {
      int s2 = (i2 < end) ? col[i2] : node;
      eP = al_s[s2 * NHEAD + head];
      xP = xh2[(size_t)s2 * 64 + lane];
    }
    e = (e > 0.f) ? e : 0.2f * e;
    float mn = fmaxf(m, e);
    float scale = __expf(m - mn);
    float p = __expf(e - mn);
    denom = denom * scale + p;
    acc0 = acc0 * scale + p * x.x;
    acc1 = acc1 * scale + p * x.y;
    m = mn;
  }
  float inv = 1.f / (denom + 1e-16f);
  int c0 = lane * 2, c1 = c0 + 1;
  float2 hr = ((const float2*)h_res)[(size_t)node * 64 + lane];
  float v0 = acc0 * inv + gb[c0] + hr.x;
  float v1 = acc1 * inv + gb[c1] + hr.y;
  float sum = v0 + v1;
  #pragma unroll
  for (int off = 32; off; off >>= 1) sum += __shfl_xor(sum, off);
  float mean = sum * (1.f / 128.f);
  float d0 = v0 - mean, d1 = v1 - mean;
  float sq = d0 * d0 + d1 * d1;
  #pragma unroll
  for (int off = 32; off; off >>= 1) sq += __shfl_xor(sq, off);
  float rstd = rsqrtf(sq * (1.f / 128.f) + 1e-5f);
  float o0 = fmaxf(d0 * rstd * lng[c0] + lnb[c0], 0.f);
  float o1 = fmaxf(d1 * rstd * lng[c1] + lnb[c1], 0.f);
  ((float2*)h_out)[(size_t)node * 64 + lane] = make_float2(o0, o1);
}

// ---------------- classifier: grid-stride, weights staged once per block ----------------
#define CLS_BLOCKS 625
__global__ __launch_bounds__(256) void classifier_kernel(
    const float* __restrict__ h, const float* __restrict__ w1,
    const float* __restrict__ b1, const float* __restrict__ w2,
    const float* __restrict__ b2, float* __restrict__ out, int n) {
  __shared__ float s_w1[128 * 64];
  __shared__ float s_w2[64 * 16];
  __shared__ float s_b1[64];
  __shared__ float s_b2[16];
  __shared__ float s_hid[4][64];
  for (int i = threadIdx.x; i < 128 * 64; i += 256) s_w1[i] = w1[i];
  for (int i = threadIdx.x; i < 64 * 16; i += 256) s_w2[i] = w2[i];
  if (threadIdx.x < 64) s_b1[threadIdx.x] = b1[threadIdx.x];
  if (threadIdx.x < 16) s_b2[threadIdx.x] = b2[threadIdx.x];
  __syncthreads();
  const int lane = threadIdx.x & 63;
  const int w = threadIdx.x >> 6;
  const int j = lane & 15;
  for (int node = blockIdx.x * 4 + w; node < n; node += CLS_BLOCKS * 4) {
    const float4* hr = (const float4*)(h + (size_t)node * 128);
    float acc = s_b1[lane];
    #pragma unroll
    for (int k4 = 0; k4 < 32; ++k4) {
      float4 hv = hr[k4];
      acc = fmaf(hv.x, s_w1[(k4 * 4 + 0) * 64 + lane], acc);
      acc = fmaf(hv.y, s_w1[(k4 * 4 + 1) * 64 + lane], acc);
      acc = fmaf(hv.z, s_w1[(k4 * 4 + 2) * 64 + lane], acc);
      acc = fmaf(hv.w, s_w1[(k4 * 4 + 3) * 64 + lane], acc);
    }
    acc = fmaxf(acc, 0.f);
    s_hid[w][lane] = acc;
    float logit = s_b2[j];
    #pragma unroll
    for (int k = 0; k < 64; ++k) logit = fmaf(s_hid[w][k], s_w2[k * 16 + j], logit);
    float mx = logit;
    #pragma unroll
    for (int off = 8; off; off >>= 1) mx = fmaxf(mx, __shfl_xor(mx, off, 16));
    float ex = __expf(logit - mx);
    float se = ex;
    #pragma unroll
    for (int off = 8; off; off >>= 1) se += __shfl_xor(se, off, 16);
    if (lane < 16) out[(size_t)node * 16 + lane] = logit - mx - __logf(se);
  }
}

// ---------------- launch ----------------
extern "C" void kernel_launch(void* const* d_in, const int* in_sizes, int n_in,
                              void* d_out, int out_size, void* d_ws, size_t ws_size,
                              hipStream_t stream) {
  const float* x       = (const float*)d_in[0];
  const int*   ei      = (const int*)d_in[1];
  const float* proj_w  = (const float*)d_in[2];
  const float* proj_b  = (const float*)d_in[3];
  const float* lin_w   = (const float*)d_in[4];
  const float* att_src = (const float*)d_in[5];
  const float* att_dst = (const float*)d_in[6];
  const float* gat_b   = (const float*)d_in[7];
  const float* ln_g    = (const float*)d_in[8];
  const float* ln_b    = (const float*)d_in[9];
  const float* cls_w1  = (const float*)d_in[10];
  const float* cls_b1  = (const float*)d_in[11];
  const float* cls_w2  = (const float*)d_in[12];
  const float* cls_b2  = (const float*)d_in[13];
  float* outp = (float*)d_out;

  const int N = NN, E = EE;
  ushort* wt  = (ushort*)d_ws;
  float* h0   = (float*)d_ws + 49152;
  float* h1   = h0 + (size_t)N * 128;
  float* xh   = h1 + (size_t)N * 128;
  float* als  = xh + (size_t)N * 128;
  float* ald  = als + (size_t)N * NHEAD;
  int* counts = (int*)(ald + (size_t)N * NHEAD);
  int* rowptr = counts + N;
  int* woff   = rowptr + N + 1;
  int* col    = woff + N;
  int* bsum   = col + E;
  int* boff   = bsum + SCAN_NBLK;

  const int* e_src = ei;
  const int* e_dst = ei + E;

  prep_weights<<<(49152 + 3 * 16384 + 255) / 256, 256, 0, stream>>>(proj_w, lin_w, wt);

  zero_ints<<<(N + 255) / 256, 256, 0, stream>>>(counts, N);
  hist_kernel<<<(E + 255) / 256, 256, 0, stream>>>(e_dst, counts, E);
  partial_sums<<<SCAN_NBLK, 256, 0, stream>>>(counts, bsum, N);
  scan_bsums<<<1, 256, 0, stream>>>(bsum, boff, SCAN_NBLK);
  final_scan<<<SCAN_NBLK, 256, 0, stream>>>(counts, boff, rowptr, woff, N);
  scatter_kernel<<<(E + 255) / 256, 256, 0, stream>>>(e_src, e_dst, woff, col, E);

  const int gblocks = (N + 127) / 128;
  mfma_gemm_n128<true><<<gblocks, 256, 0, stream>>>(x, wt, proj_b, h0, N, DIN);

  float* hc = h0;
  float* hn = h1;
  for (int l = 0; l < 3; ++l) {
    mfma_gemm_n128<false><<<gblocks, 256, 0, stream>>>(
        hc, wt + 49152 + l * 16384, nullptr, xh, N, 128);
    att_logits_kernel<<<(N * NHEAD + 255) / 256, 256, 0, stream>>>(
        xh, att_src + l * 128, att_dst + l * 128, als, ald, N);
    gat_aggregate<<<(N + 3) / 4, 256, 0, stream>>>(
        xh, als, ald, rowptr, col, hc, gat_b + l * 128, ln_g + l * 128,
        ln_b + l * 128, hn, N);
    float* t = hc; hc = hn; hn = t;
  }
  classifier_kernel<<<CLS_BLOCKS, 256, 0, stream>>>(hc, cls_w1, cls_b1, cls_w2, cls_b2, outp, N);
}

// Round 5
// 511.999 us; speedup vs baseline: 1.5050x; 1.1308x over previous
//
#include <hip/hip_runtime.h>
#include <hip/hip_bf16.h>
#include <math.h>

#define NN 50000
#define EE 500000
#define DIN 384
#define HIDD 128
#define NHEAD 8
#define OUTD 16

typedef __attribute__((ext_vector_type(8))) __bf16 bf16x8;
typedef __attribute__((ext_vector_type(4))) float f32x4;

__device__ __forceinline__ ushort f2bf(float f) {
  union { float f; unsigned u; } v; v.f = f;
  unsigned r = v.u + 0x7fffu + ((v.u >> 16) & 1u);
  return (ushort)(r >> 16);
}

// ---------------- CSR build ----------------
__global__ void zero_ints(int* p, int n) {
  int i = blockIdx.x * blockDim.x + threadIdx.x;
  if (i < n) p[i] = 0;
}

__global__ void hist_kernel(const int* __restrict__ dst, int* __restrict__ counts, int e) {
  int i = blockIdx.x * blockDim.x + threadIdx.x;
  if (i < e) atomicAdd(&counts[dst[i]], 1);
}

// ---- hierarchical scan: 196 blocks of 256, all passes coalesced ----
#define SCAN_BS 256
#define SCAN_NBLK ((NN + SCAN_BS - 1) / SCAN_BS)  // 196

__global__ __launch_bounds__(256) void partial_sums(const int* __restrict__ counts,
                                                    int* __restrict__ bsum, int n) {
  __shared__ int red[256];
  int i = blockIdx.x * 256 + threadIdx.x;
  red[threadIdx.x] = (i < n) ? counts[i] : 0;
  __syncthreads();
  #pragma unroll
  for (int off = 128; off; off >>= 1) {
    if (threadIdx.x < off) red[threadIdx.x] += red[threadIdx.x + off];
    __syncthreads();
  }
  if (threadIdx.x == 0) bsum[blockIdx.x] = red[0];
}

__global__ __launch_bounds__(256) void scan_bsums(const int* __restrict__ bsum,
                                                  int* __restrict__ boff, int nb) {
  __shared__ int buf[256];
  int t = threadIdx.x;
  int v = (t < nb) ? bsum[t] : 0;
  buf[t] = v;
  __syncthreads();
  #pragma unroll
  for (int off = 1; off < 256; off <<= 1) {
    int u = (t >= off) ? buf[t - off] : 0;
    __syncthreads();
    buf[t] += u;
    __syncthreads();
  }
  if (t < nb) boff[t] = buf[t] - v;
}

__global__ __launch_bounds__(256) void final_scan(const int* __restrict__ counts,
                                                  const int* __restrict__ boff,
                                                  int* __restrict__ rowptr,
                                                  int* __restrict__ woff, int n) {
  __shared__ int buf[256];
  int i = blockIdx.x * 256 + threadIdx.x;
  int t = threadIdx.x;
  int v = (i < n) ? counts[i] : 0;
  buf[t] = v;
  __syncthreads();
  #pragma unroll
  for (int off = 1; off < 256; off <<= 1) {
    int u = (t >= off) ? buf[t - off] : 0;
    __syncthreads();
    buf[t] += u;
    __syncthreads();
  }
  int excl = boff[blockIdx.x] + buf[t] - v;
  if (i < n) { rowptr[i] = excl; woff[i] = excl; }
  if (i == n - 1) rowptr[n] = excl + v;
}

__global__ void scatter_kernel(const int* __restrict__ src, const int* __restrict__ dst,
                               int* __restrict__ woff, int* __restrict__ col, int e) {
  int i = blockIdx.x * blockDim.x + threadIdx.x;
  if (i < e) {
    int p = atomicAdd(&woff[dst[i]], 1);
    col[p] = src[i];
  }
}

// ---------------- weight prep ----------------
// wt layout (ushort):
//  [0..49151]          proj_wt [n=128][k=384]
//  [49152 + l*16384]   lin_wt_l [n=128][k=128]   (l=0..2)
//  [98304..106495]     cls_w1t [n=64][k=128]
//  [106496..107519]    cls_w2t [n=16][k=64]
__global__ void prep_weights(const float* __restrict__ proj_w,
                             const float* __restrict__ lin_w,
                             const float* __restrict__ cls_w1,
                             const float* __restrict__ cls_w2,
                             ushort* __restrict__ wt) {
  int i = blockIdx.x * blockDim.x + threadIdx.x;
  if (i < 49152) {
    int k = i >> 7, n = i & 127;
    wt[n * 384 + k] = f2bf(proj_w[i]);
  } else if (i < 98304) {
    int j = i - 49152;
    int l = j >> 14, rem = j & 16383;
    int k = rem >> 7, n = rem & 127;
    wt[49152 + l * 16384 + n * 128 + k] = f2bf(lin_w[j]);
  } else if (i < 106496) {
    int j = i - 98304;
    int n = j >> 7, k = j & 127;
    wt[98304 + n * 128 + k] = f2bf(cls_w1[k * 64 + n]);
  } else if (i < 107520) {
    int j = i - 106496;
    int n = j >> 6, k = j & 63;
    wt[106496 + n * 64 + k] = f2bf(cls_w2[k * 16 + n]);
  }
}

// ---------------- MFMA GEMM: C[M,128] = A[M,K] @ B[K,128] ----------------
#define LDS_STRIDE 72  // 64 + 8 pad: 144 B row stride -> 2-way bank alias (free, m136)
template<bool RELU_BIAS>
__global__ __launch_bounds__(256) void mfma_gemm_n128(const float* __restrict__ A,
                                                      const ushort* __restrict__ Bt,
                                                      const float* __restrict__ bias,
                                                      float* __restrict__ C, int M, int K) {
  __shared__ ushort sA[128 * LDS_STRIDE];
  __shared__ ushort sB[128 * LDS_STRIDE];
  const int tid = threadIdx.x;
  const int wave = tid >> 6, lane = tid & 63;
  const int q = lane >> 4, lm = lane & 15;
  const int wr = wave >> 1, wc = wave & 1;
  const int m0 = blockIdx.x * 128;

  f32x4 acc[4][4];
  #pragma unroll
  for (int i = 0; i < 4; i++)
    #pragma unroll
    for (int j = 0; j < 4; j++) acc[i][j] = {0.f, 0.f, 0.f, 0.f};

  for (int k0 = 0; k0 < K; k0 += 64) {
    __syncthreads();
    #pragma unroll
    for (int p = 0; p < 8; ++p) {
      int idx = p * 256 + tid;
      int r = idx >> 4;
      int c = (idx & 15) << 2;
      float4 v = make_float4(0.f, 0.f, 0.f, 0.f);
      if (m0 + r < M) v = *(const float4*)(A + (size_t)(m0 + r) * K + k0 + c);
      ushort4 u;
      u.x = f2bf(v.x); u.y = f2bf(v.y); u.z = f2bf(v.z); u.w = f2bf(v.w);
      *(ushort4*)&sA[r * LDS_STRIDE + c] = u;
    }
    #pragma unroll
    for (int p = 0; p < 4; ++p) {
      int idx = p * 256 + tid;
      int r = idx >> 3;
      int c = (idx & 7) << 3;
      bf16x8 v = *(const bf16x8*)(Bt + (size_t)r * K + k0 + c);
      *(bf16x8*)&sB[r * LDS_STRIDE + c] = v;
    }
    __syncthreads();
    #pragma unroll
    for (int ks = 0; ks < 2; ++ks) {
      bf16x8 af[4], bfv[4];
      #pragma unroll
      for (int t = 0; t < 4; ++t) {
        af[t]  = *(const bf16x8*)&sA[(wr * 64 + t * 16 + lm) * LDS_STRIDE + ks * 32 + q * 8];
        bfv[t] = *(const bf16x8*)&sB[(wc * 64 + t * 16 + lm) * LDS_STRIDE + ks * 32 + q * 8];
      }
      #pragma unroll
      for (int i = 0; i < 4; ++i)
        #pragma unroll
        for (int j = 0; j < 4; ++j)
          acc[i][j] = __builtin_amdgcn_mfma_f32_16x16x32_bf16(af[i], bfv[j], acc[i][j], 0, 0, 0);
    }
  }
  #pragma unroll
  for (int i = 0; i < 4; ++i) {
    #pragma unroll
    for (int r = 0; r < 4; ++r) {
      int row = m0 + wr * 64 + i * 16 + q * 4 + r;
      if (row < M) {
        #pragma unroll
        for (int j = 0; j < 4; ++j) {
          int colc = wc * 64 + j * 16 + lm;
          float v = acc[i][j][r];
          if (RELU_BIAS) { v += bias[colc]; v = fmaxf(v, 0.f); }
          C[(size_t)row * 128 + colc] = v;
        }
      }
    }
  }
}

// ---------------- attention logits ----------------
__global__ void att_logits_kernel(const float* __restrict__ xh,
                                  const float* __restrict__ att_s,
                                  const float* __restrict__ att_d,
                                  float* __restrict__ al_s, float* __restrict__ al_d, int n) {
  int t = blockIdx.x * blockDim.x + threadIdx.x;
  if (t >= n * NHEAD) return;
  int head = t & 7;
  const float4* xr = (const float4*)(xh + (size_t)t * 16);
  const float4* as = (const float4*)(att_s + head * 16);
  const float4* ad = (const float4*)(att_d + head * 16);
  float ss = 0.f, dd = 0.f;
  #pragma unroll
  for (int i = 0; i < 4; i++) {
    float4 x = xr[i], a = as[i], b = ad[i];
    ss += x.x * a.x + x.y * a.y + x.z * a.z + x.w * a.w;
    dd += x.x * b.x + x.y * b.y + x.z * b.z + x.w * b.w;
  }
  al_s[t] = ss;
  al_d[t] = dd;
}

// ---------------- GAT aggregation: one wave per node, online softmax, 1-deep prefetch ----
__global__ __launch_bounds__(256) void gat_aggregate(
    const float* __restrict__ xh, const float* __restrict__ al_s,
    const float* __restrict__ al_d, const int* __restrict__ rowptr,
    const int* __restrict__ col, const float* __restrict__ h_res,
    const float* __restrict__ gb, const float* __restrict__ lng,
    const float* __restrict__ lnb, float* __restrict__ h_out, int n) {
  int lane = threadIdx.x & 63;
  int node = (blockIdx.x * blockDim.x + threadIdx.x) >> 6;
  if (node >= n) return;
  int head = lane >> 3;
  const float2* xh2 = (const float2*)xh;
  float ald = al_d[node * NHEAD + head];
  int start = rowptr[node], end = rowptr[node + 1];
  int sP = (start < end) ? col[start] : node;
  float eP = al_s[sP * NHEAD + head];
  float2 xP = xh2[(size_t)sP * 64 + lane];
  float m = -INFINITY, denom = 0.f, acc0 = 0.f, acc1 = 0.f;
  for (int i = start; i <= end; ++i) {   // last iteration = self loop
    float e = eP + ald;
    float2 x = xP;
    int i2 = i + 1;
    if (i2 <= end) {
      int s2 = (i2 < end) ? col[i2] : node;
      eP = al_s[s2 * NHEAD + head];
      xP = xh2[(size_t)s2 * 64 + lane];
    }
    e = (e > 0.f) ? e : 0.2f * e;
    float mn = fmaxf(m, e);
    float scale = __expf(m - mn);
    float p = __expf(e - mn);
    denom = denom * scale + p;
    acc0 = acc0 * scale + p * x.x;
    acc1 = acc1 * scale + p * x.y;
    m = mn;
  }
  float inv = 1.f / (denom + 1e-16f);
  int c0 = lane * 2, c1 = c0 + 1;
  float2 hr = ((const float2*)h_res)[(size_t)node * 64 + lane];
  float v0 = acc0 * inv + gb[c0] + hr.x;
  float v1 = acc1 * inv + gb[c1] + hr.y;
  float sum = v0 + v1;
  #pragma unroll
  for (int off = 32; off; off >>= 1) sum += __shfl_xor(sum, off);
  float mean = sum * (1.f / 128.f);
  float d0 = v0 - mean, d1 = v1 - mean;
  float sq = d0 * d0 + d1 * d1;
  #pragma unroll
  for (int off = 32; off; off >>= 1) sq += __shfl_xor(sq, off);
  float rstd = rsqrtf(sq * (1.f / 128.f) + 1e-5f);
  float o0 = fmaxf(d0 * rstd * lng[c0] + lnb[c0], 0.f);
  float o1 = fmaxf(d1 * rstd * lng[c1] + lnb[c1], 0.f);
  ((float2*)h_out)[(size_t)node * 64 + lane] = make_float2(o0, o1);
}

// ---------------- MFMA classifier: relu(h@w1+b1)@w2+b2 -> log_softmax ----------------
#define CSTR 136  // 128+8 pad: 272 B row stride -> 2-way bank alias (free)
#define HSTR 72
__global__ __launch_bounds__(256) void classifier_mfma(
    const float* __restrict__ h, const ushort* __restrict__ w1t,
    const float* __restrict__ b1, const ushort* __restrict__ w2t,
    const float* __restrict__ b2, float* __restrict__ out, int n) {
  __shared__ ushort sA[128 * CSTR];     // h tile bf16
  __shared__ ushort sB[64 * CSTR];      // w1t bf16
  __shared__ ushort sHid[128 * HSTR];   // hid bf16 (C-layout -> A-layout round trip)
  const int tid = threadIdx.x;
  const int wave = tid >> 6, lane = tid & 63;
  const int q = lane >> 4, lm = lane & 15;
  const int wr = wave >> 1, wc = wave & 1;
  const int m0 = blockIdx.x * 128;

  // stage h [128 x 128] fp32 -> bf16 (coalesced float4)
  #pragma unroll
  for (int p = 0; p < 16; ++p) {
    int idx = p * 256 + tid;
    int r = idx >> 5;
    int c = (idx & 31) << 2;
    float4 v = make_float4(0.f, 0.f, 0.f, 0.f);
    if (m0 + r < n) v = *(const float4*)(h + (size_t)(m0 + r) * 128 + c);
    ushort4 u;
    u.x = f2bf(v.x); u.y = f2bf(v.y); u.z = f2bf(v.z); u.w = f2bf(v.w);
    *(ushort4*)&sA[r * CSTR + c] = u;
  }
  // stage w1t [64 x 128] bf16
  #pragma unroll
  for (int p = 0; p < 4; ++p) {
    int idx = p * 256 + tid;
    int r = idx >> 4;
    int c = (idx & 15) << 3;
    *(bf16x8*)&sB[r * CSTR + c] = *(const bf16x8*)(w1t + r * 128 + c);
  }
  __syncthreads();

  // GEMM1: [128x128]@[128x64]; wave (wr,wc): rows wr*64.., cols wc*32..
  f32x4 acc[4][2];
  #pragma unroll
  for (int i = 0; i < 4; ++i)
    #pragma unroll
    for (int j = 0; j < 2; ++j) acc[i][j] = {0.f, 0.f, 0.f, 0.f};
  #pragma unroll
  for (int ks = 0; ks < 4; ++ks) {
    bf16x8 af[4], bfv[2];
    #pragma unroll
    for (int t = 0; t < 4; ++t)
      af[t] = *(const bf16x8*)&sA[(wr * 64 + t * 16 + lm) * CSTR + ks * 32 + q * 8];
    #pragma unroll
    for (int j = 0; j < 2; ++j)
      bfv[j] = *(const bf16x8*)&sB[(wc * 32 + j * 16 + lm) * CSTR + ks * 32 + q * 8];
    #pragma unroll
    for (int i = 0; i < 4; ++i)
      #pragma unroll
      for (int j = 0; j < 2; ++j)
        acc[i][j] = __builtin_amdgcn_mfma_f32_16x16x32_bf16(af[i], bfv[j], acc[i][j], 0, 0, 0);
  }
  // bias + relu, C-layout -> sHid
  #pragma unroll
  for (int i = 0; i < 4; ++i) {
    #pragma unroll
    for (int j = 0; j < 2; ++j) {
      int colc = wc * 32 + j * 16 + lm;
      float bb = b1[colc];
      #pragma unroll
      for (int r = 0; r < 4; ++r) {
        int row = wr * 64 + i * 16 + q * 4 + r;
        float v = fmaxf(acc[i][j][r] + bb, 0.f);
        sHid[row * HSTR + colc] = f2bf(v);
      }
    }
  }
  __syncthreads();

  // GEMM2: [128x64]@[64x16]; wave handles rows wave*32..wave*32+31
  f32x4 acc2[2] = {{0.f, 0.f, 0.f, 0.f}, {0.f, 0.f, 0.f, 0.f}};
  #pragma unroll
  for (int ks = 0; ks < 2; ++ks) {
    bf16x8 b2f = *(const bf16x8*)(w2t + lm * 64 + ks * 32 + q * 8);  // tiny, L1-resident
    #pragma unroll
    for (int t = 0; t < 2; ++t) {
      bf16x8 a2 = *(const bf16x8*)&sHid[(wave * 32 + t * 16 + lm) * HSTR + ks * 32 + q * 8];
      acc2[t] = __builtin_amdgcn_mfma_f32_16x16x32_bf16(a2, b2f, acc2[t], 0, 0, 0);
    }
  }
  // epilogue: +b2, row-wise log_softmax over 16 cols (cols live in 16 lanes of quad)
  float bb2 = b2[lm];
  #pragma unroll
  for (int t = 0; t < 2; ++t) {
    #pragma unroll
    for (int r = 0; r < 4; ++r) {
      int row = m0 + wave * 32 + t * 16 + q * 4 + r;
      float lg = acc2[t][r] + bb2;
      float mx = lg;
      #pragma unroll
      for (int off = 8; off; off >>= 1) mx = fmaxf(mx, __shfl_xor(mx, off, 16));
      float se = __expf(lg - mx);
      #pragma unroll
      for (int off = 8; off; off >>= 1) se += __shfl_xor(se, off, 16);
      if (row < n) out[(size_t)row * 16 + lm] = lg - mx - __logf(se);
    }
  }
}

// ---------------- launch ----------------
extern "C" void kernel_launch(void* const* d_in, const int* in_sizes, int n_in,
                              void* d_out, int out_size, void* d_ws, size_t ws_size,
                              hipStream_t stream) {
  const float* x       = (const float*)d_in[0];
  const int*   ei      = (const int*)d_in[1];
  const float* proj_w  = (const float*)d_in[2];
  const float* proj_b  = (const float*)d_in[3];
  const float* lin_w   = (const float*)d_in[4];
  const float* att_src = (const float*)d_in[5];
  const float* att_dst = (const float*)d_in[6];
  const float* gat_b   = (const float*)d_in[7];
  const float* ln_g    = (const float*)d_in[8];
  const float* ln_b    = (const float*)d_in[9];
  const float* cls_w1  = (const float*)d_in[10];
  const float* cls_b1  = (const float*)d_in[11];
  const float* cls_w2  = (const float*)d_in[12];
  const float* cls_b2  = (const float*)d_in[13];
  float* outp = (float*)d_out;

  const int N = NN, E = EE;
  ushort* wt  = (ushort*)d_ws;                  // 107520 ushorts -> pad to 108544 (even floats)
  float* h0   = (float*)d_ws + 54272;
  float* h1   = h0 + (size_t)N * 128;
  float* xh   = h1 + (size_t)N * 128;
  float* als  = xh + (size_t)N * 128;
  float* ald  = als + (size_t)N * NHEAD;
  int* counts = (int*)(ald + (size_t)N * NHEAD);
  int* rowptr = counts + N;
  int* woff   = rowptr + N + 1;
  int* col    = woff + N;
  int* bsum   = col + E;
  int* boff   = bsum + SCAN_NBLK;

  const int* e_src = ei;
  const int* e_dst = ei + E;

  prep_weights<<<(107520 + 255) / 256, 256, 0, stream>>>(proj_w, lin_w, cls_w1, cls_w2, wt);

  zero_ints<<<(N + 255) / 256, 256, 0, stream>>>(counts, N);
  hist_kernel<<<(E + 255) / 256, 256, 0, stream>>>(e_dst, counts, E);
  partial_sums<<<SCAN_NBLK, 256, 0, stream>>>(counts, bsum, N);
  scan_bsums<<<1, 256, 0, stream>>>(bsum, boff, SCAN_NBLK);
  final_scan<<<SCAN_NBLK, 256, 0, stream>>>(counts, boff, rowptr, woff, N);
  scatter_kernel<<<(E + 255) / 256, 256, 0, stream>>>(e_src, e_dst, woff, col, E);

  const int gblocks = (N + 127) / 128;
  mfma_gemm_n128<true><<<gblocks, 256, 0, stream>>>(x, wt, proj_b, h0, N, DIN);

  float* hc = h0;
  float* hn = h1;
  for (int l = 0; l < 3; ++l) {
    mfma_gemm_n128<false><<<gblocks, 256, 0, stream>>>(
        hc, wt + 49152 + l * 16384, nullptr, xh, N, 128);
    att_logits_kernel<<<(N * NHEAD + 255) / 256, 256, 0, stream>>>(
        xh, att_src + l * 128, att_dst + l * 128, als, ald, N);
    gat_aggregate<<<(N + 3) / 4, 256, 0, stream>>>(
        xh, als, ald, rowptr, col, hc, gat_b + l * 128, ln_g + l * 128,
        ln_b + l * 128, hn, N);
    float* t = hc; hc = hn; hn = t;
  }
  classifier_mfma<<<gblocks, 256, 0, stream>>>(hc, wt + 98304, cls_b1, wt + 106496, cls_b2, outp, N);
}